// Round 4
// baseline (183.175 us; speedup 1.0000x reference)
//
#include <hip/hip_runtime.h>
#include <stdint.h>

// Problem constants
#define NN 16384                  // sampled points per batch (h*w)
#define HW 65536                  // H*W
#define OUT_HALF (2 * NN * 128)   // one tuple element, flat floats
// MLP: 67 -> 64 -> 64 -> 128 (BN folded), maxpool over K=32 neighbors.
//
// One wave = one point (32 neighbors = M rows of 16x16x32 bf16 MFMAs).
// fp32 accuracy via hi/lo bf16 split, 3 passes: ah*wh + al*wh + ah*wl.
// Waves are fully independent (private LDS tile) -> NO __syncthreads;
// intra-wave cross-lane LDS ordering via s_waitcnt lgkmcnt(0) + sched_barrier.
// LDS = 4 waves x [32][64] f32 XOR-swizzled = exactly 32 KiB -> 5 blocks/CU.
// Swizzle: elem index = row*64 + (col ^ ((row&7)<<2)); uniform bank load for
// fragment reads, gather float4 writes, and scalar writebacks (verified by
// hand: every access pattern hits each bank equally).
//
// Fragment maps (gfx950 16x16x32 bf16, m89-verified):
//   A: row = lane&15, k = 8*(lane>>4)+e ;  B: col = lane&15, same k
//   C/D: col = lane&15, row = 4*(lane>>4)+reg

typedef __attribute__((ext_vector_type(8))) short bf16x8;
typedef __attribute__((ext_vector_type(4))) float f32x4;

// ws layout, uint16 units:
#define WS_L0H 0
#define WS_L0L 6144
#define WS_L1H 12288
#define WS_L1L 16384
#define WS_L2H 20480
#define WS_L2L 28672
#define WS_BIAS 36864

__device__ inline uint16_t f32_to_bf16_rne(float x) {
    uint32_t u = __float_as_uint(x);
    uint32_t r = (u + 0x7FFFu + ((u >> 16) & 1u)) >> 16;
    return (uint16_t)r;
}
__device__ inline float bf16_hi_f32(uint16_t h) {
    return __uint_as_float(((uint32_t)h) << 16);
}
__device__ inline void split2(float v, uint16_t* hi, uint16_t* lo) {
    uint16_t h = f32_to_bf16_rne(v);
    *hi = h;
    *lo = f32_to_bf16_rne(v - bf16_hi_f32(h));
}

// ---------------- weight prep (runs once per launch, tiny) ----------------
__global__ void prep_weights(
    const float* __restrict__ W0, const float* __restrict__ b0,
    const float* __restrict__ g0, const float* __restrict__ be0,
    const float* __restrict__ W1, const float* __restrict__ b1,
    const float* __restrict__ g1, const float* __restrict__ be1,
    const float* __restrict__ W2, const float* __restrict__ b2,
    const float* __restrict__ g2, const float* __restrict__ be2,
    uint16_t* __restrict__ ws)
{
    const int tid = blockIdx.x * blockDim.x + threadIdx.x;
    const int nth = gridDim.x * blockDim.x;

    // L0: [3 kt][4 nt][64 lane][8 e]; k 0..63 -> W0 row 3+k, 64..66 -> row k-64
    for (int i = tid; i < 6144; i += nth) {
        int e = i & 7, lane = (i >> 3) & 63, nt = (i >> 9) & 3, kt = i >> 11;
        int k = kt * 32 + 8 * (lane >> 4) + e;
        int n = nt * 16 + (lane & 15);
        float v = 0.f;
        if (k < 64)       v = W0[(3 + k) * 64 + n] * g0[n];
        else if (k < 67)  v = W0[(k - 64) * 64 + n] * g0[n];
        uint16_t hi, lo; split2(v, &hi, &lo);
        ws[WS_L0H + i] = hi; ws[WS_L0L + i] = lo;
    }
    for (int i = tid; i < 4096; i += nth) {
        int e = i & 7, lane = (i >> 3) & 63, nt = (i >> 9) & 3, kt = i >> 11;
        int k = kt * 32 + 8 * (lane >> 4) + e;
        int n = nt * 16 + (lane & 15);
        float v = W1[k * 64 + n] * g1[n];
        uint16_t hi, lo; split2(v, &hi, &lo);
        ws[WS_L1H + i] = hi; ws[WS_L1L + i] = lo;
    }
    for (int i = tid; i < 8192; i += nth) {
        int e = i & 7, lane = (i >> 3) & 63, nt = (i >> 9) & 7, kt = i >> 12;
        int k = kt * 32 + 8 * (lane >> 4) + e;
        int n = nt * 16 + (lane & 15);
        float v = W2[k * 128 + n] * g2[n];
        uint16_t hi, lo; split2(v, &hi, &lo);
        ws[WS_L2H + i] = hi; ws[WS_L2L + i] = lo;
    }
    float* bias = (float*)(ws + WS_BIAS);
    for (int i = tid; i < 64; i += nth)  bias[i]       = b0[i] * g0[i] + be0[i];
    for (int i = tid; i < 64; i += nth)  bias[64 + i]  = b1[i] * g1[i] + be1[i];
    for (int i = tid; i < 128; i += nth) bias[128 + i] = b2[i] * g2[i] + be2[i];
}

// ---------------- main kernel helpers ----------------
__device__ inline uint32_t cvt_pk_bf16(float a, float b) {
    uint32_t r;
    asm("v_cvt_pk_bf16_f32 %0, %1, %2" : "=v"(r) : "v"(a), "v"(b));
    return r;
}

union frag_u { uint32_t w[4]; bf16x8 v; };

// split 8 f32 -> hi/lo bf16x8 via packed converts (lo = a - f32(hi), exact)
__device__ inline void split8(const float* f, bf16x8* hi, bf16x8* lo) {
    frag_u H, L;
    #pragma unroll
    for (int p2 = 0; p2 < 4; ++p2) {
        float a = f[2 * p2], b = f[2 * p2 + 1];
        uint32_t h = cvt_pk_bf16(a, b);
        float ha = __uint_as_float(h << 16);
        float hb = __uint_as_float(h & 0xffff0000u);
        uint32_t l = cvt_pk_bf16(a - ha, b - hb);
        H.w[p2] = h; L.w[p2] = l;
    }
    *hi = H.v; *lo = L.v;
}

__device__ inline f32x4 mfma3(bf16x8 ah, bf16x8 al, bf16x8 wh, bf16x8 wl, f32x4 c) {
    c = __builtin_amdgcn_mfma_f32_16x16x32_bf16(ah, wh, c, 0, 0, 0);
    c = __builtin_amdgcn_mfma_f32_16x16x32_bf16(al, wh, c, 0, 0, 0);
    c = __builtin_amdgcn_mfma_f32_16x16x32_bf16(ah, wl, c, 0, 0, 0);
    return c;
}

// swizzled f32 tile [32][64]: elem = row*64 + (col ^ ((row&7)<<2))
__device__ inline void load_frag(const float* tile, int row, int c0, float* f) {
    const int sw = (row & 7) << 2;
    *(float4*)&f[0] = *(const float4*)&tile[row * 64 + (c0 ^ sw)];
    *(float4*)&f[4] = *(const float4*)&tile[row * 64 + ((c0 + 4) ^ sw)];
}

#define WAVE_LDS_FENCE() do { \
    asm volatile("s_waitcnt lgkmcnt(0)" ::: "memory"); \
    __builtin_amdgcn_sched_barrier(0); \
} while (0)

__global__ __launch_bounds__(256, 5)
void pointnet_mfma(
    const float* __restrict__ xyz_proj,      // [B, H*W, 3]
    const float* __restrict__ points_proj,   // [B, H*W, 64]
    const float* __restrict__ xyz_sampled,   // [B, N, 3]
    const int*   __restrict__ nidx,          // [B, N, 32]
    const float* __restrict__ vmask,         // [B, N, 32, 1]
    const uint16_t* __restrict__ wf,
    float* __restrict__ out)
{
    __shared__ float s_feat[4][2048];   // exactly 32 KiB -> 5 blocks/CU

    const int t    = threadIdx.x & 63;
    const int widx = threadIdx.x >> 6;
    const int p    = blockIdx.x * 4 + widx;   // point id in [0, 2*NN)
    const int b    = p >> 14;                  // NN = 16384

    float* tile = s_feat[widx];

    const bf16x8* L0h = (const bf16x8*)(wf + WS_L0H);
    const bf16x8* L0l = (const bf16x8*)(wf + WS_L0L);
    const bf16x8* L1h = (const bf16x8*)(wf + WS_L1H);
    const bf16x8* L1l = (const bf16x8*)(wf + WS_L1L);
    const bf16x8* L2h = (const bf16x8*)(wf + WS_L2H);
    const bf16x8* L2l = (const bf16x8*)(wf + WS_L2L);
    const float*  bias = (const float*)(wf + WS_BIAS);

    // ---- gather: 32 rows x 64 ch into swizzled tile; xyz_diff in regs ----
    const int r  = t & 31;
    const int hh = t >> 5;
    const int   idx = nidx[(size_t)p * 32 + r];
    const float m   = vmask[(size_t)p * 32 + r];
    {
        const float* src = points_proj + ((size_t)b * HW + idx) * 64 + hh * 32;
        const int sw = (r & 7) << 2;
        #pragma unroll
        for (int q = 0; q < 8; ++q) {
            float4 v = ((const float4*)src)[q];
            v.x *= m; v.y *= m; v.z *= m; v.w *= m;
            const int c0 = hh * 32 + 4 * q;
            *(float4*)&tile[r * 64 + (c0 ^ sw)] = v;
        }
    }
    // xyz_diff for row r, held in regs by both hh-halves (sources are lanes 0..31)
    float xd0, xd1, xd2;
    {
        const float* xs = xyz_proj + ((size_t)b * HW + idx) * 3;
        xd0 = xs[0] * m - xyz_sampled[(size_t)p * 3 + 0];
        xd1 = xs[1] * m - xyz_sampled[(size_t)p * 3 + 1];
        xd2 = xs[2] * m - xyz_sampled[(size_t)p * 3 + 2];
    }

    WAVE_LDS_FENCE();

    // ---- layer 0: K = 64 (pts) + 3 (xyz) -> 64 ----
    f32x4 acc0[2][4] = {};
    #pragma unroll
    for (int kt = 0; kt < 2; ++kt) {
        bf16x8 ah[2], al[2];
        #pragma unroll
        for (int mt = 0; mt < 2; ++mt) {
            float f[8];
            load_frag(tile, mt * 16 + (t & 15), kt * 32 + 8 * (t >> 4), f);
            split8(f, &ah[mt], &al[mt]);
        }
        #pragma unroll
        for (int nt = 0; nt < 4; ++nt) {
            bf16x8 wh = L0h[(kt * 4 + nt) * 64 + t];
            bf16x8 wl = L0l[(kt * 4 + nt) * 64 + t];
            #pragma unroll
            for (int mt = 0; mt < 2; ++mt)
                acc0[mt][nt] = mfma3(ah[mt], al[mt], wh, wl, acc0[mt][nt]);
        }
    }
    {   // xyz k-step (kt=2): lanes g==0 carry e=0..2; rest zero
        const int srow = t & 15;
        float a0 = __shfl(xd0, srow),      a1 = __shfl(xd1, srow),      a2 = __shfl(xd2, srow);
        float c0 = __shfl(xd0, srow + 16), c1 = __shfl(xd1, srow + 16), c2 = __shfl(xd2, srow + 16);
        const bool g0 = (t >> 4) == 0;
        float f0[8] = { g0 ? a0 : 0.f, g0 ? a1 : 0.f, g0 ? a2 : 0.f, 0.f, 0.f, 0.f, 0.f, 0.f };
        float f1[8] = { g0 ? c0 : 0.f, g0 ? c1 : 0.f, g0 ? c2 : 0.f, 0.f, 0.f, 0.f, 0.f, 0.f };
        bf16x8 ah[2], al[2];
        split8(f0, &ah[0], &al[0]);
        split8(f1, &ah[1], &al[1]);
        #pragma unroll
        for (int nt = 0; nt < 4; ++nt) {
            bf16x8 wh = L0h[(8 + nt) * 64 + t];
            bf16x8 wl = L0l[(8 + nt) * 64 + t];
            #pragma unroll
            for (int mt = 0; mt < 2; ++mt)
                acc0[mt][nt] = mfma3(ah[mt], al[mt], wh, wl, acc0[mt][nt]);
        }
    }
    {   // bias + relu -> writeback (swizzled)
        float bb[4];
        #pragma unroll
        for (int nt = 0; nt < 4; ++nt) bb[nt] = bias[nt * 16 + (t & 15)];
        #pragma unroll
        for (int mt = 0; mt < 2; ++mt)
            #pragma unroll
            for (int nt = 0; nt < 4; ++nt)
                #pragma unroll
                for (int rr = 0; rr < 4; ++rr) {
                    float y = acc0[mt][nt][rr] + bb[nt];
                    y = y > 0.f ? y : 0.f;
                    const int row = mt * 16 + (t >> 4) * 4 + rr;
                    const int col = nt * 16 + (t & 15);
                    tile[row * 64 + (col ^ ((row & 7) << 2))] = y;
                }
    }

    WAVE_LDS_FENCE();

    // ---- layer 1: 64 -> 64 ----
    f32x4 acc1[2][4] = {};
    #pragma unroll
    for (int kt = 0; kt < 2; ++kt) {
        bf16x8 ah[2], al[2];
        #pragma unroll
        for (int mt = 0; mt < 2; ++mt) {
            float f[8];
            load_frag(tile, mt * 16 + (t & 15), kt * 32 + 8 * (t >> 4), f);
            split8(f, &ah[mt], &al[mt]);
        }
        #pragma unroll
        for (int nt = 0; nt < 4; ++nt) {
            bf16x8 wh = L1h[(kt * 4 + nt) * 64 + t];
            bf16x8 wl = L1l[(kt * 4 + nt) * 64 + t];
            #pragma unroll
            for (int mt = 0; mt < 2; ++mt)
                acc1[mt][nt] = mfma3(ah[mt], al[mt], wh, wl, acc1[mt][nt]);
        }
    }
    {
        float bb[4];
        #pragma unroll
        for (int nt = 0; nt < 4; ++nt) bb[nt] = bias[64 + nt * 16 + (t & 15)];
        #pragma unroll
        for (int mt = 0; mt < 2; ++mt)
            #pragma unroll
            for (int nt = 0; nt < 4; ++nt)
                #pragma unroll
                for (int rr = 0; rr < 4; ++rr) {
                    float y = acc1[mt][nt][rr] + bb[nt];
                    y = y > 0.f ? y : 0.f;
                    const int row = mt * 16 + (t >> 4) * 4 + rr;
                    const int col = nt * 16 + (t & 15);
                    tile[row * 64 + (col ^ ((row & 7) << 2))] = y;
                }
    }

    WAVE_LDS_FENCE();

    // ---- layer 2: 64 -> 128, fused maxpool + store ----
    bf16x8 a2h[2][2], a2l[2][2];   // [kt][mt]
    #pragma unroll
    for (int kt = 0; kt < 2; ++kt)
        #pragma unroll
        for (int mt = 0; mt < 2; ++mt) {
            float f[8];
            load_frag(tile, mt * 16 + (t & 15), kt * 32 + 8 * (t >> 4), f);
            split8(f, &a2h[kt][mt], &a2l[kt][mt]);
        }

    #pragma unroll
    for (int nh = 0; nh < 2; ++nh) {
        f32x4 acc[2][4] = {};
        #pragma unroll
        for (int kt = 0; kt < 2; ++kt)
            #pragma unroll
            for (int nt = 0; nt < 4; ++nt) {
                bf16x8 wh = L2h[(kt * 8 + nh * 4 + nt) * 64 + t];
                bf16x8 wl = L2l[(kt * 8 + nh * 4 + nt) * 64 + t];
                #pragma unroll
                for (int mt = 0; mt < 2; ++mt)
                    acc[mt][nt] = mfma3(a2h[kt][mt], a2l[kt][mt], wh, wl, acc[mt][nt]);
            }
        float vnt[4];
        #pragma unroll
        for (int nt = 0; nt < 4; ++nt) {
            float bb = bias[128 + nh * 64 + nt * 16 + (t & 15)];
            float mx = acc[0][nt][0];
            #pragma unroll
            for (int rr = 1; rr < 4; ++rr) mx = fmaxf(mx, acc[0][nt][rr]);
            #pragma unroll
            for (int rr = 0; rr < 4; ++rr) mx = fmaxf(mx, acc[1][nt][rr]);
            float v = mx + bb;
            v = v > 0.f ? v : 0.f;            // relu commutes with max
            v = fmaxf(v, __shfl_xor(v, 16));
            v = fmaxf(v, __shfl_xor(v, 32));
            vnt[nt] = v;
        }
        const int g = t >> 4;
        float v01 = (g & 1) ? vnt[1] : vnt[0];
        float v23 = (g & 1) ? vnt[3] : vnt[2];
        float val = (g & 2) ? v23 : v01;
        size_t o = (size_t)p * 128 + nh * 64 + t;
        out[o] = val;
        out[o + OUT_HALF] = val;
    }
}

extern "C" void kernel_launch(void* const* d_in, const int* in_sizes, int n_in,
                              void* d_out, int out_size, void* d_ws, size_t ws_size,
                              hipStream_t stream) {
    const float* xyz_proj    = (const float*)d_in[0];
    const float* points_proj = (const float*)d_in[1];
    const float* xyz_sampled = (const float*)d_in[2];
    const int*   neighbor_idx= (const int*)  d_in[3];
    const float* valid_mask  = (const float*)d_in[4];
    const float* W0 = (const float*)d_in[5];
    const float* b0 = (const float*)d_in[6];
    const float* g0 = (const float*)d_in[7];
    const float* be0= (const float*)d_in[8];
    const float* W1 = (const float*)d_in[9];
    const float* b1 = (const float*)d_in[10];
    const float* g1 = (const float*)d_in[11];
    const float* be1= (const float*)d_in[12];
    const float* W2 = (const float*)d_in[13];
    const float* b2 = (const float*)d_in[14];
    const float* g2 = (const float*)d_in[15];
    const float* be2= (const float*)d_in[16];

    uint16_t* ws = (uint16_t*)d_ws;

    prep_weights<<<64, 256, 0, stream>>>(W0, b0, g0, be0,
                                         W1, b1, g1, be1,
                                         W2, b2, g2, be2, ws);

    pointnet_mfma<<<8192, 256, 0, stream>>>(
        xyz_proj, points_proj, xyz_sampled, neighbor_idx, valid_mask,
        ws, (float*)d_out);
}

// Round 5
// 142.796 us; speedup vs baseline: 1.2828x; 1.2828x over previous
//
#include <hip/hip_runtime.h>
#include <stdint.h>

// Problem constants
#define NN 16384                  // sampled points per batch (h*w)
#define HW 65536                  // H*W
#define OUT_HALF (2 * NN * 128)   // one tuple element, flat floats
// MLP: 67 -> 64 -> 64 -> 128 (BN folded), maxpool over K=32 neighbors.
//
// One wave = one point (32 neighbors = M rows of 16x16x32 bf16 MFMAs).
// fp32 accuracy via hi/lo bf16 split, 3 passes: ah*wh + al*wh + ah*wl.
// Waves are fully independent (private LDS tile) -> NO __syncthreads;
// intra-wave cross-lane LDS ordering via s_waitcnt lgkmcnt(0) + sched_barrier.
// LDS = 4 waves x [32][64] f32 XOR-swizzled = exactly 32 KiB -> 5 blocks/CU.
// NOTE round-4 lesson: __launch_bounds__(256,5) forced VGPR=48 -> 90 MB of
// scratch spills (WRITE_SIZE 122 MB) and a regression. Plain (256) gives the
// allocator ~60-72 VGPR with zero spill.
// XCD swizzle (T1): grid 8192 %8==0; each XCD gets a contiguous 1024-block
// chunk = 4096 consecutive points; their gather window ~4 MB = one L2.
//
// Fragment maps (gfx950 16x16x32 bf16, m89-verified):
//   A: row = lane&15, k = 8*(lane>>4)+e ;  B: col = lane&15, same k
//   C/D: col = lane&15, row = 4*(lane>>4)+reg

typedef __attribute__((ext_vector_type(8))) short bf16x8;
typedef __attribute__((ext_vector_type(4))) float f32x4;

// ws layout, uint16 units:
#define WS_L0H 0
#define WS_L0L 6144
#define WS_L1H 12288
#define WS_L1L 16384
#define WS_L2H 20480
#define WS_L2L 28672
#define WS_BIAS 36864

__device__ inline uint16_t f32_to_bf16_rne(float x) {
    uint32_t u = __float_as_uint(x);
    uint32_t r = (u + 0x7FFFu + ((u >> 16) & 1u)) >> 16;
    return (uint16_t)r;
}
__device__ inline float bf16_hi_f32(uint16_t h) {
    return __uint_as_float(((uint32_t)h) << 16);
}
__device__ inline void split2(float v, uint16_t* hi, uint16_t* lo) {
    uint16_t h = f32_to_bf16_rne(v);
    *hi = h;
    *lo = f32_to_bf16_rne(v - bf16_hi_f32(h));
}

// ---------------- weight prep (runs once per launch, tiny) ----------------
__global__ void prep_weights(
    const float* __restrict__ W0, const float* __restrict__ b0,
    const float* __restrict__ g0, const float* __restrict__ be0,
    const float* __restrict__ W1, const float* __restrict__ b1,
    const float* __restrict__ g1, const float* __restrict__ be1,
    const float* __restrict__ W2, const float* __restrict__ b2,
    const float* __restrict__ g2, const float* __restrict__ be2,
    uint16_t* __restrict__ ws)
{
    const int tid = blockIdx.x * blockDim.x + threadIdx.x;
    const int nth = gridDim.x * blockDim.x;

    // L0: [3 kt][4 nt][64 lane][8 e]; k 0..63 -> W0 row 3+k, 64..66 -> row k-64
    for (int i = tid; i < 6144; i += nth) {
        int e = i & 7, lane = (i >> 3) & 63, nt = (i >> 9) & 3, kt = i >> 11;
        int k = kt * 32 + 8 * (lane >> 4) + e;
        int n = nt * 16 + (lane & 15);
        float v = 0.f;
        if (k < 64)       v = W0[(3 + k) * 64 + n] * g0[n];
        else if (k < 67)  v = W0[(k - 64) * 64 + n] * g0[n];
        uint16_t hi, lo; split2(v, &hi, &lo);
        ws[WS_L0H + i] = hi; ws[WS_L0L + i] = lo;
    }
    for (int i = tid; i < 4096; i += nth) {
        int e = i & 7, lane = (i >> 3) & 63, nt = (i >> 9) & 3, kt = i >> 11;
        int k = kt * 32 + 8 * (lane >> 4) + e;
        int n = nt * 16 + (lane & 15);
        float v = W1[k * 64 + n] * g1[n];
        uint16_t hi, lo; split2(v, &hi, &lo);
        ws[WS_L1H + i] = hi; ws[WS_L1L + i] = lo;
    }
    for (int i = tid; i < 8192; i += nth) {
        int e = i & 7, lane = (i >> 3) & 63, nt = (i >> 9) & 7, kt = i >> 12;
        int k = kt * 32 + 8 * (lane >> 4) + e;
        int n = nt * 16 + (lane & 15);
        float v = W2[k * 128 + n] * g2[n];
        uint16_t hi, lo; split2(v, &hi, &lo);
        ws[WS_L2H + i] = hi; ws[WS_L2L + i] = lo;
    }
    float* bias = (float*)(ws + WS_BIAS);
    for (int i = tid; i < 64; i += nth)  bias[i]       = b0[i] * g0[i] + be0[i];
    for (int i = tid; i < 64; i += nth)  bias[64 + i]  = b1[i] * g1[i] + be1[i];
    for (int i = tid; i < 128; i += nth) bias[128 + i] = b2[i] * g2[i] + be2[i];
}

// ---------------- main kernel helpers ----------------
__device__ inline uint32_t cvt_pk_bf16(float a, float b) {
    uint32_t r;
    asm("v_cvt_pk_bf16_f32 %0, %1, %2" : "=v"(r) : "v"(a), "v"(b));
    return r;
}

union frag_u { uint32_t w[4]; bf16x8 v; };

// split 8 f32 -> hi/lo bf16x8 via packed converts (lo = a - f32(hi), exact)
__device__ inline void split8(const float* f, bf16x8* hi, bf16x8* lo) {
    frag_u H, L;
    #pragma unroll
    for (int p2 = 0; p2 < 4; ++p2) {
        float a = f[2 * p2], b = f[2 * p2 + 1];
        uint32_t h = cvt_pk_bf16(a, b);
        float ha = __uint_as_float(h << 16);
        float hb = __uint_as_float(h & 0xffff0000u);
        uint32_t l = cvt_pk_bf16(a - ha, b - hb);
        H.w[p2] = h; L.w[p2] = l;
    }
    *hi = H.v; *lo = L.v;
}

__device__ inline f32x4 mfma3(bf16x8 ah, bf16x8 al, bf16x8 wh, bf16x8 wl, f32x4 c) {
    c = __builtin_amdgcn_mfma_f32_16x16x32_bf16(ah, wh, c, 0, 0, 0);
    c = __builtin_amdgcn_mfma_f32_16x16x32_bf16(al, wh, c, 0, 0, 0);
    c = __builtin_amdgcn_mfma_f32_16x16x32_bf16(ah, wl, c, 0, 0, 0);
    return c;
}

// swizzled f32 tile [32][64]: elem = row*64 + (col ^ ((row&7)<<2))
__device__ inline void load_frag(const float* tile, int row, int c0, float* f) {
    const int sw = (row & 7) << 2;
    *(float4*)&f[0] = *(const float4*)&tile[row * 64 + (c0 ^ sw)];
    *(float4*)&f[4] = *(const float4*)&tile[row * 64 + ((c0 + 4) ^ sw)];
}

#define WAVE_LDS_FENCE() do { \
    asm volatile("s_waitcnt lgkmcnt(0)" ::: "memory"); \
    __builtin_amdgcn_sched_barrier(0); \
} while (0)

__global__ __launch_bounds__(256)
void pointnet_mfma(
    const float* __restrict__ xyz_proj,      // [B, H*W, 3]
    const float* __restrict__ points_proj,   // [B, H*W, 64]
    const float* __restrict__ xyz_sampled,   // [B, N, 3]
    const int*   __restrict__ nidx,          // [B, N, 32]
    const float* __restrict__ vmask,         // [B, N, 32, 1]
    const uint16_t* __restrict__ wf,
    float* __restrict__ out)
{
    __shared__ float s_feat[4][2048];   // exactly 32 KiB -> 5 blocks/CU

    // XCD-aware bijective swizzle (grid 8192, 8 XCDs, 1024 blocks per XCD)
    const int bid = blockIdx.x;
    const int swz = (bid & 7) * 1024 + (bid >> 3);

    const int t    = threadIdx.x & 63;
    const int widx = threadIdx.x >> 6;
    const int p    = swz * 4 + widx;          // point id in [0, 2*NN)
    const int b    = p >> 14;                  // NN = 16384

    float* tile = s_feat[widx];

    const bf16x8* L0h = (const bf16x8*)(wf + WS_L0H);
    const bf16x8* L0l = (const bf16x8*)(wf + WS_L0L);
    const bf16x8* L1h = (const bf16x8*)(wf + WS_L1H);
    const bf16x8* L1l = (const bf16x8*)(wf + WS_L1L);
    const bf16x8* L2h = (const bf16x8*)(wf + WS_L2H);
    const bf16x8* L2l = (const bf16x8*)(wf + WS_L2L);
    const float*  bias = (const float*)(wf + WS_BIAS);

    // ---- gather: 32 rows x 64 ch into swizzled tile; xyz_diff in regs ----
    const int r  = t & 31;
    const int hh = t >> 5;
    const int   idx = nidx[(size_t)p * 32 + r];
    const float m   = vmask[(size_t)p * 32 + r];
    {
        const float* src = points_proj + ((size_t)b * HW + idx) * 64 + hh * 32;
        const int sw = (r & 7) << 2;
        #pragma unroll
        for (int q = 0; q < 8; ++q) {
            float4 v = ((const float4*)src)[q];
            v.x *= m; v.y *= m; v.z *= m; v.w *= m;
            const int c0 = hh * 32 + 4 * q;
            *(float4*)&tile[r * 64 + (c0 ^ sw)] = v;
        }
    }
    // xyz_diff for row r (lanes t and t+32 compute identical values)
    float xd0, xd1, xd2;
    {
        const float* xs = xyz_proj + ((size_t)b * HW + idx) * 3;
        xd0 = xs[0] * m - xyz_sampled[(size_t)p * 3 + 0];
        xd1 = xs[1] * m - xyz_sampled[(size_t)p * 3 + 1];
        xd2 = xs[2] * m - xyz_sampled[(size_t)p * 3 + 2];
    }

    WAVE_LDS_FENCE();

    // ---- layer 0: K = 64 (pts) + 3 (xyz) -> 64 ----
    f32x4 acc0[2][4] = {};
    #pragma unroll
    for (int kt = 0; kt < 2; ++kt) {
        bf16x8 ah[2], al[2];
        #pragma unroll
        for (int mt = 0; mt < 2; ++mt) {
            float f[8];
            load_frag(tile, mt * 16 + (t & 15), kt * 32 + 8 * (t >> 4), f);
            split8(f, &ah[mt], &al[mt]);
        }
        #pragma unroll
        for (int nt = 0; nt < 4; ++nt) {
            bf16x8 wh = L0h[(kt * 4 + nt) * 64 + t];
            bf16x8 wl = L0l[(kt * 4 + nt) * 64 + t];
            #pragma unroll
            for (int mt = 0; mt < 2; ++mt)
                acc0[mt][nt] = mfma3(ah[mt], al[mt], wh, wl, acc0[mt][nt]);
        }
    }
    {   // xyz k-step (kt=2): lanes g==0 carry e=0..2; rest zero
        const int srow = t & 15;
        float a0 = __shfl(xd0, srow),      a1 = __shfl(xd1, srow),      a2 = __shfl(xd2, srow);
        float c0 = __shfl(xd0, srow + 16), c1 = __shfl(xd1, srow + 16), c2 = __shfl(xd2, srow + 16);
        const bool g0 = (t >> 4) == 0;
        float f0[8] = { g0 ? a0 : 0.f, g0 ? a1 : 0.f, g0 ? a2 : 0.f, 0.f, 0.f, 0.f, 0.f, 0.f };
        float f1[8] = { g0 ? c0 : 0.f, g0 ? c1 : 0.f, g0 ? c2 : 0.f, 0.f, 0.f, 0.f, 0.f, 0.f };
        bf16x8 ah[2], al[2];
        split8(f0, &ah[0], &al[0]);
        split8(f1, &ah[1], &al[1]);
        #pragma unroll
        for (int nt = 0; nt < 4; ++nt) {
            bf16x8 wh = L0h[(8 + nt) * 64 + t];
            bf16x8 wl = L0l[(8 + nt) * 64 + t];
            #pragma unroll
            for (int mt = 0; mt < 2; ++mt)
                acc0[mt][nt] = mfma3(ah[mt], al[mt], wh, wl, acc0[mt][nt]);
        }
    }
    {   // bias + relu -> writeback (swizzled)
        float bb[4];
        #pragma unroll
        for (int nt = 0; nt < 4; ++nt) bb[nt] = bias[nt * 16 + (t & 15)];
        #pragma unroll
        for (int mt = 0; mt < 2; ++mt)
            #pragma unroll
            for (int nt = 0; nt < 4; ++nt)
                #pragma unroll
                for (int rr = 0; rr < 4; ++rr) {
                    float y = acc0[mt][nt][rr] + bb[nt];
                    y = y > 0.f ? y : 0.f;
                    const int row = mt * 16 + (t >> 4) * 4 + rr;
                    const int col = nt * 16 + (t & 15);
                    tile[row * 64 + (col ^ ((row & 7) << 2))] = y;
                }
    }

    WAVE_LDS_FENCE();

    // ---- layer 1: 64 -> 64 ----
    f32x4 acc1[2][4] = {};
    #pragma unroll
    for (int kt = 0; kt < 2; ++kt) {
        bf16x8 ah[2], al[2];
        #pragma unroll
        for (int mt = 0; mt < 2; ++mt) {
            float f[8];
            load_frag(tile, mt * 16 + (t & 15), kt * 32 + 8 * (t >> 4), f);
            split8(f, &ah[mt], &al[mt]);
        }
        #pragma unroll
        for (int nt = 0; nt < 4; ++nt) {
            bf16x8 wh = L1h[(kt * 4 + nt) * 64 + t];
            bf16x8 wl = L1l[(kt * 4 + nt) * 64 + t];
            #pragma unroll
            for (int mt = 0; mt < 2; ++mt)
                acc1[mt][nt] = mfma3(ah[mt], al[mt], wh, wl, acc1[mt][nt]);
        }
    }
    {
        float bb[4];
        #pragma unroll
        for (int nt = 0; nt < 4; ++nt) bb[nt] = bias[64 + nt * 16 + (t & 15)];
        #pragma unroll
        for (int mt = 0; mt < 2; ++mt)
            #pragma unroll
            for (int nt = 0; nt < 4; ++nt)
                #pragma unroll
                for (int rr = 0; rr < 4; ++rr) {
                    float y = acc1[mt][nt][rr] + bb[nt];
                    y = y > 0.f ? y : 0.f;
                    const int row = mt * 16 + (t >> 4) * 4 + rr;
                    const int col = nt * 16 + (t & 15);
                    tile[row * 64 + (col ^ ((row & 7) << 2))] = y;
                }
    }

    WAVE_LDS_FENCE();

    // ---- layer 2: 64 -> 128, fused maxpool + store ----
    bf16x8 a2h[2][2], a2l[2][2];   // [kt][mt]
    #pragma unroll
    for (int kt = 0; kt < 2; ++kt)
        #pragma unroll
        for (int mt = 0; mt < 2; ++mt) {
            float f[8];
            load_frag(tile, mt * 16 + (t & 15), kt * 32 + 8 * (t >> 4), f);
            split8(f, &a2h[kt][mt], &a2l[kt][mt]);
        }

    #pragma unroll
    for (int nh = 0; nh < 2; ++nh) {
        f32x4 acc[2][4] = {};
        #pragma unroll
        for (int kt = 0; kt < 2; ++kt)
            #pragma unroll
            for (int nt = 0; nt < 4; ++nt) {
                bf16x8 wh = L2h[(kt * 8 + nh * 4 + nt) * 64 + t];
                bf16x8 wl = L2l[(kt * 8 + nh * 4 + nt) * 64 + t];
                #pragma unroll
                for (int mt = 0; mt < 2; ++mt)
                    acc[mt][nt] = mfma3(a2h[kt][mt], a2l[kt][mt], wh, wl, acc[mt][nt]);
            }
        float vnt[4];
        #pragma unroll
        for (int nt = 0; nt < 4; ++nt) {
            float bb = bias[128 + nh * 64 + nt * 16 + (t & 15)];
            float mx = acc[0][nt][0];
            #pragma unroll
            for (int rr = 1; rr < 4; ++rr) mx = fmaxf(mx, acc[0][nt][rr]);
            #pragma unroll
            for (int rr = 0; rr < 4; ++rr) mx = fmaxf(mx, acc[1][nt][rr]);
            float v = mx + bb;
            v = v > 0.f ? v : 0.f;            // relu commutes with max
            v = fmaxf(v, __shfl_xor(v, 16));
            v = fmaxf(v, __shfl_xor(v, 32));
            vnt[nt] = v;
        }
        const int g = t >> 4;
        float v01 = (g & 1) ? vnt[1] : vnt[0];
        float v23 = (g & 1) ? vnt[3] : vnt[2];
        float val = (g & 2) ? v23 : v01;
        size_t o = (size_t)p * 128 + nh * 64 + t;
        out[o] = val;
        out[o + OUT_HALF] = val;
    }
}

extern "C" void kernel_launch(void* const* d_in, const int* in_sizes, int n_in,
                              void* d_out, int out_size, void* d_ws, size_t ws_size,
                              hipStream_t stream) {
    const float* xyz_proj    = (const float*)d_in[0];
    const float* points_proj = (const float*)d_in[1];
    const float* xyz_sampled = (const float*)d_in[2];
    const int*   neighbor_idx= (const int*)  d_in[3];
    const float* valid_mask  = (const float*)d_in[4];
    const float* W0 = (const float*)d_in[5];
    const float* b0 = (const float*)d_in[6];
    const float* g0 = (const float*)d_in[7];
    const float* be0= (const float*)d_in[8];
    const float* W1 = (const float*)d_in[9];
    const float* b1 = (const float*)d_in[10];
    const float* g1 = (const float*)d_in[11];
    const float* be1= (const float*)d_in[12];
    const float* W2 = (const float*)d_in[13];
    const float* b2 = (const float*)d_in[14];
    const float* g2 = (const float*)d_in[15];
    const float* be2= (const float*)d_in[16];

    uint16_t* ws = (uint16_t*)d_ws;

    prep_weights<<<64, 256, 0, stream>>>(W0, b0, g0, be0,
                                         W1, b1, g1, be1,
                                         W2, b2, g2, be2, ws);

    pointnet_mfma<<<8192, 256, 0, stream>>>(
        xyz_proj, points_proj, xyz_sampled, neighbor_idx, valid_mask,
        ws, (float*)d_out);
}